// Round 3
// baseline (1020.018 us; speedup 1.0000x reference)
//
#include <hip/hip_runtime.h>
#include <math.h>

// CentroidInstanceLoss: N=2M points, D=16, B=8 subbatches, M=32 labels.
// out = (L_pull + L_push)/B  (single fp32 scalar)
//
// R3 structure: 4 lanes per point (one float4/lane/iter, fully coalesced),
// shfl_xor cross-lane reductions, 2048 blocks for 32 waves/CU occupancy.
// R2 lesson: bottleneck was serialized per-thread load chains at 2 waves/SIMD,
// not atomics.

#define DD 16
#define MM 32
#define BBATCH 8
#define SEGS 256          // B*M
#define DELTA_V 0.5f
#define DELTA_D 1.5f
#define NEPS 1e-8f

#define NBLK 2048
#define NTHR 256
#define PLANE 257         // padded plane stride: group's 4 lanes -> distinct banks

// ws layout (floats):
//   [0,4096)        seg_sum   [seg][d]    (HW fp atomics)
//   [4096,4352)     seg_cnt   [seg]
//   [4352,8448)     mus       [seg][d]
//   [8448,8704)     invw      [seg]   = 1/(M*count)
//   [8704]          push_acc
//   [8720,8720+2048) pull_part [NBLK]
#define WS_ZERO_FLOATS 4352

__device__ __forceinline__ float block_reduce_sum(float v) {
    #pragma unroll
    for (int o = 32; o > 0; o >>= 1) v += __shfl_down(v, o, 64);
    __shared__ float red[4];
    int wid  = threadIdx.x >> 6;
    int lane = threadIdx.x & 63;
    if (lane == 0) red[wid] = v;
    __syncthreads();
    v = (threadIdx.x < (NTHR >> 6)) ? red[threadIdx.x] : 0.0f;
    if (wid == 0) {
        #pragma unroll
        for (int o = 32; o > 0; o >>= 1) v += __shfl_down(v, o, 64);
    }
    return v;  // valid on thread 0
}

__global__ void __launch_bounds__(NTHR, 8)
k_segsum(const float4* __restrict__ o4,
         const int* __restrict__ labels,
         const int* __restrict__ sub,
         float* __restrict__ seg_sum,
         float* __restrict__ seg_cnt,
         int n4) {
    __shared__ float lsT[DD * PLANE];   // [dim][seg], padded stride
    __shared__ float lcnt[SEGS];
    for (int i = threadIdx.x; i < DD * PLANE; i += NTHR) lsT[i] = 0.0f;
    for (int i = threadIdx.x; i < SEGS; i += NTHR) lcnt[i] = 0.0f;
    __syncthreads();

    const int S = NBLK * NTHR;
    for (int q = blockIdx.x * NTHR + threadIdx.x; q < n4; q += S) {
        float4 v = o4[q];                 // 16 B/lane, consecutive lanes consecutive addrs
        int p = q >> 2;
        int j = q & 3;                    // which dim-quad of the point
        int seg = sub[p] * MM + labels[p];
        float ss = v.x*v.x + v.y*v.y + v.z*v.z + v.w*v.w;
        ss += __shfl_xor(ss, 1, 64);
        ss += __shfl_xor(ss, 2, 64);      // all 4 lanes of the point have full ||x||^2
        float rn = 1.0f / (sqrtf(ss) + NEPS);
        float* base = &lsT[(4 * j) * PLANE + seg];
        unsafeAtomicAdd(base,             v.x * rn);
        unsafeAtomicAdd(base + PLANE,     v.y * rn);
        unsafeAtomicAdd(base + 2 * PLANE, v.z * rn);
        unsafeAtomicAdd(base + 3 * PLANE, v.w * rn);
        if (j == 0) unsafeAtomicAdd(&lcnt[seg], 1.0f);
    }
    __syncthreads();
    // flush: hardware fp32 global atomics
    for (int s = threadIdx.x; s < SEGS; s += NTHR) {
        #pragma unroll
        for (int d = 0; d < DD; ++d)
            unsafeAtomicAdd(&seg_sum[s * DD + d], lsT[d * PLANE + s]);
        unsafeAtomicAdd(&seg_cnt[s], lcnt[s]);
    }
}

__global__ void k_finalize_push(float* __restrict__ ws) {
    const float* seg_sum = ws;
    const float* seg_cnt = ws + 4096;
    float* mus  = ws + 4352;
    float* invw = ws + 8448;
    float* push = ws + 8704;

    __shared__ float muT[DD * SEGS];
    int t = threadIdx.x;  // 256 threads == one per segment
    float cnt = seg_cnt[t];
    float ic  = (cnt > 0.0f) ? 1.0f / cnt : 0.0f;
    #pragma unroll
    for (int d = 0; d < DD; ++d) {
        float m = seg_sum[t * DD + d] * ic;
        mus[t * DD + d]   = m;
        muT[d * SEGS + t] = m;
    }
    invw[t] = (cnt > 0.0f) ? 1.0f / ((float)MM * cnt) : 0.0f;
    __syncthreads();

    int b = t >> 5, m1 = t & 31;
    float acc = 0.0f;
    for (int m2 = 0; m2 < MM; ++m2) {
        float pd = 0.0f;
        #pragma unroll
        for (int d = 0; d < DD; ++d)
            pd += fabsf(muT[d * SEGS + b * MM + m1] - muT[d * SEGS + b * MM + m2]);
        float h = 2.0f * DELTA_D - pd;
        if (m2 != m1 && h > 0.0f) acc += h * h;
    }
    float tot = block_reduce_sum(acc);
    if (t == 0) push[0] = tot / (float)(MM * (MM - 1));
}

__global__ void __launch_bounds__(NTHR, 8)
k_pull(const float4* __restrict__ o4,
       const int* __restrict__ labels,
       const int* __restrict__ sub,
       const float* __restrict__ mus,
       const float* __restrict__ invw,
       float* __restrict__ pull_part,
       int n4) {
    __shared__ float muL[DD * SEGS];  // [seg][d] seg-major, float4-aligned reads
    __shared__ float siw[SEGS];
    for (int i = threadIdx.x; i < DD * SEGS; i += NTHR) muL[i] = mus[i];
    for (int i = threadIdx.x; i < SEGS; i += NTHR) siw[i] = invw[i];
    __syncthreads();

    float acc = 0.0f;
    const int S = NBLK * NTHR;
    for (int q = blockIdx.x * NTHR + threadIdx.x; q < n4; q += S) {
        float4 v = o4[q];
        int p = q >> 2;
        int j = q & 3;
        int seg = sub[p] * MM + labels[p];
        float ss = v.x*v.x + v.y*v.y + v.z*v.z + v.w*v.w;
        ss += __shfl_xor(ss, 1, 64);
        ss += __shfl_xor(ss, 2, 64);
        float rn = 1.0f / (sqrtf(ss) + NEPS);
        const float4 m = *(const float4*)&muL[seg * DD + 4 * j];
        float d4 = fabsf(m.x - v.x * rn) + fabsf(m.y - v.y * rn)
                 + fabsf(m.z - v.z * rn) + fabsf(m.w - v.w * rn);
        d4 += __shfl_xor(d4, 1, 64);
        d4 += __shfl_xor(d4, 2, 64);      // full L1 distance on all 4 lanes
        if (j == 0) {
            float h = d4 - DELTA_V;
            if (h > 0.0f) acc = fmaf(h * h, siw[seg], acc);
        }
    }
    float tot = block_reduce_sum(acc);
    if (threadIdx.x == 0) pull_part[blockIdx.x] = tot;
}

__global__ void k_final(const float* __restrict__ ws, float* __restrict__ out) {
    const float* push      = ws + 8704;
    const float* pull_part = ws + 8720;
    int t = threadIdx.x;
    float v = 0.0f;
    #pragma unroll
    for (int k = 0; k < NBLK / NTHR; ++k) v += pull_part[t + k * NTHR];
    float tot = block_reduce_sum(v);
    if (t == 0) out[0] = (tot + push[0]) * (1.0f / (float)BBATCH);
}

extern "C" void kernel_launch(void* const* d_in, const int* in_sizes, int n_in,
                              void* d_out, int out_size, void* d_ws, size_t ws_size,
                              hipStream_t stream) {
    const float* outputs = (const float*)d_in[0];
    const int* labels    = (const int*)d_in[1];
    const int* sub       = (const int*)d_in[2];
    int n  = in_sizes[0] / DD;
    int n4 = n * 4;

    float* ws        = (float*)d_ws;
    float* seg_sum   = ws;
    float* seg_cnt   = ws + 4096;
    float* mus       = ws + 4352;
    float* invw      = ws + 8448;
    float* pull_part = ws + 8720;

    hipMemsetAsync(d_ws, 0, WS_ZERO_FLOATS * sizeof(float), stream);

    k_segsum<<<NBLK, NTHR, 0, stream>>>((const float4*)outputs, labels, sub,
                                        seg_sum, seg_cnt, n4);
    k_finalize_push<<<1, NTHR, 0, stream>>>(ws);
    k_pull<<<NBLK, NTHR, 0, stream>>>((const float4*)outputs, labels, sub,
                                      mus, invw, pull_part, n4);
    k_final<<<1, NTHR, 0, stream>>>(ws, (float*)d_out);
}

// Round 4
// 309.056 us; speedup vs baseline: 3.3004x; 3.3004x over previous
//
#include <hip/hip_runtime.h>
#include <math.h>

// CentroidInstanceLoss: N=2M points, D=16, B=8 subbatches, M=32 labels.
// out = (L_pull + L_push)/B  (single fp32 scalar)
//
// R4: register-resident segment accumulation. R2/R3 lesson: in-loop LDS
// atomics (~6 cyc/lane-op) were the wall (invisible in VALUBusy/HBM counters).
// Each block owns a contiguous chunk; per-lane seg is loop-invariant for the
// canonical input, so acc lives in VGPRs and LDS atomics fire only on seg
// change / loop end. Fully correct for arbitrary labels via the change-flush.

#define DD 16
#define MM 32
#define BBATCH 8
#define SEGS 256          // B*M
#define DELTA_V 0.5f
#define DELTA_D 1.5f
#define NEPS 1e-8f

#define NBLK 1024
#define NTHR 256
#define CHUNK 2048        // points per block = N / NBLK (guarded anyway)

// ws layout (floats):
//   [0,4096)        seg_sum   [seg][d]    (HW fp atomics)
//   [4096,4352)     seg_cnt   [seg]
//   [4352,8448)     mus       [seg][d]  (seg-major)
//   [8448,8704)     invw      [seg]   = 1/(M*count)
//   [8704]          push_acc
//   [8720,8720+NBLK) pull_part
#define WS_ZERO_FLOATS 4352

__device__ __forceinline__ void lds_fadd(float* p, float v) {
    __hip_atomic_fetch_add(p, v, __ATOMIC_RELAXED, __HIP_MEMORY_SCOPE_WORKGROUP);
}

__device__ __forceinline__ float block_reduce_sum(float v) {
    #pragma unroll
    for (int o = 32; o > 0; o >>= 1) v += __shfl_down(v, o, 64);
    __shared__ float red[4];
    int wid  = threadIdx.x >> 6;
    int lane = threadIdx.x & 63;
    if (lane == 0) red[wid] = v;
    __syncthreads();
    v = (threadIdx.x < (NTHR >> 6)) ? red[threadIdx.x] : 0.0f;
    if (wid == 0) {
        #pragma unroll
        for (int o = 32; o > 0; o >>= 1) v += __shfl_down(v, o, 64);
    }
    return v;  // valid on thread 0
}

__global__ void __launch_bounds__(NTHR, 4)
k_segsum(const float4* __restrict__ o4,
         const int* __restrict__ labels,
         const int* __restrict__ sub,
         float* __restrict__ seg_sum,
         float* __restrict__ seg_cnt,
         int n) {
    __shared__ float lsT[(DD + 1) * SEGS];  // planes [d][seg]; plane 16 = count
    for (int i = threadIdx.x; i < (DD + 1) * SEGS; i += NTHR) lsT[i] = 0.0f;
    __syncthreads();

    float4 a0 = {0,0,0,0}, a1 = {0,0,0,0}, a2 = {0,0,0,0}, a3 = {0,0,0,0};
    float cnt = 0.0f;
    int cur = -1;

    const int base = blockIdx.x * CHUNK + threadIdx.x;
    #pragma unroll
    for (int it = 0; it < CHUNK / NTHR; ++it) {
        int p = base + it * NTHR;
        if (p >= n) break;
        float4 a = o4[4 * p + 0];
        float4 b = o4[4 * p + 1];
        float4 c = o4[4 * p + 2];
        float4 e = o4[4 * p + 3];
        int seg = sub[p] * MM + labels[p];
        float ss = a.x*a.x + a.y*a.y + a.z*a.z + a.w*a.w
                 + b.x*b.x + b.y*b.y + b.z*b.z + b.w*b.w
                 + c.x*c.x + c.y*c.y + c.z*c.z + c.w*c.w
                 + e.x*e.x + e.y*e.y + e.z*e.z + e.w*e.w;
        float rn = 1.0f / (sqrtf(ss) + NEPS);
        if (seg != cur) {              // rare (never for canonical input)
            if (cur >= 0) {
                lds_fadd(&lsT[ 0*SEGS + cur], a0.x); lds_fadd(&lsT[ 1*SEGS + cur], a0.y);
                lds_fadd(&lsT[ 2*SEGS + cur], a0.z); lds_fadd(&lsT[ 3*SEGS + cur], a0.w);
                lds_fadd(&lsT[ 4*SEGS + cur], a1.x); lds_fadd(&lsT[ 5*SEGS + cur], a1.y);
                lds_fadd(&lsT[ 6*SEGS + cur], a1.z); lds_fadd(&lsT[ 7*SEGS + cur], a1.w);
                lds_fadd(&lsT[ 8*SEGS + cur], a2.x); lds_fadd(&lsT[ 9*SEGS + cur], a2.y);
                lds_fadd(&lsT[10*SEGS + cur], a2.z); lds_fadd(&lsT[11*SEGS + cur], a2.w);
                lds_fadd(&lsT[12*SEGS + cur], a3.x); lds_fadd(&lsT[13*SEGS + cur], a3.y);
                lds_fadd(&lsT[14*SEGS + cur], a3.z); lds_fadd(&lsT[15*SEGS + cur], a3.w);
                lds_fadd(&lsT[16*SEGS + cur], cnt);
            }
            a0 = a1 = a2 = a3 = (float4){0,0,0,0};
            cnt = 0.0f;
            cur = seg;
        }
        a0.x += a.x * rn; a0.y += a.y * rn; a0.z += a.z * rn; a0.w += a.w * rn;
        a1.x += b.x * rn; a1.y += b.y * rn; a1.z += b.z * rn; a1.w += b.w * rn;
        a2.x += c.x * rn; a2.y += c.y * rn; a2.z += c.z * rn; a2.w += c.w * rn;
        a3.x += e.x * rn; a3.y += e.y * rn; a3.z += e.z * rn; a3.w += e.w * rn;
        cnt += 1.0f;
    }
    if (cur >= 0) {
        lds_fadd(&lsT[ 0*SEGS + cur], a0.x); lds_fadd(&lsT[ 1*SEGS + cur], a0.y);
        lds_fadd(&lsT[ 2*SEGS + cur], a0.z); lds_fadd(&lsT[ 3*SEGS + cur], a0.w);
        lds_fadd(&lsT[ 4*SEGS + cur], a1.x); lds_fadd(&lsT[ 5*SEGS + cur], a1.y);
        lds_fadd(&lsT[ 6*SEGS + cur], a1.z); lds_fadd(&lsT[ 7*SEGS + cur], a1.w);
        lds_fadd(&lsT[ 8*SEGS + cur], a2.x); lds_fadd(&lsT[ 9*SEGS + cur], a2.y);
        lds_fadd(&lsT[10*SEGS + cur], a2.z); lds_fadd(&lsT[11*SEGS + cur], a2.w);
        lds_fadd(&lsT[12*SEGS + cur], a3.x); lds_fadd(&lsT[13*SEGS + cur], a3.y);
        lds_fadd(&lsT[14*SEGS + cur], a3.z); lds_fadd(&lsT[15*SEGS + cur], a3.w);
        lds_fadd(&lsT[16*SEGS + cur], cnt);
    }
    __syncthreads();
    // global flush: only segments this block actually touched (count != 0)
    for (int s = threadIdx.x; s < SEGS; s += NTHR) {
        float c = lsT[DD * SEGS + s];
        if (c != 0.0f) {
            #pragma unroll
            for (int d = 0; d < DD; ++d)
                unsafeAtomicAdd(&seg_sum[s * DD + d], lsT[d * SEGS + s]);
            unsafeAtomicAdd(&seg_cnt[s], c);
        }
    }
}

__global__ void k_finalize_push(float* __restrict__ ws) {
    const float* seg_sum = ws;
    const float* seg_cnt = ws + 4096;
    float* mus  = ws + 4352;
    float* invw = ws + 8448;
    float* push = ws + 8704;

    __shared__ float muT[DD * SEGS];
    int t = threadIdx.x;  // 256 threads == one per segment
    float cnt = seg_cnt[t];
    float ic  = (cnt > 0.0f) ? 1.0f / cnt : 0.0f;
    #pragma unroll
    for (int d = 0; d < DD; ++d) {
        float m = seg_sum[t * DD + d] * ic;
        mus[t * DD + d]   = m;
        muT[d * SEGS + t] = m;
    }
    invw[t] = (cnt > 0.0f) ? 1.0f / ((float)MM * cnt) : 0.0f;
    __syncthreads();

    int b = t >> 5, m1 = t & 31;
    float acc = 0.0f;
    for (int m2 = 0; m2 < MM; ++m2) {
        float pd = 0.0f;
        #pragma unroll
        for (int d = 0; d < DD; ++d)
            pd += fabsf(muT[d * SEGS + b * MM + m1] - muT[d * SEGS + b * MM + m2]);
        float h = 2.0f * DELTA_D - pd;
        if (m2 != m1 && h > 0.0f) acc += h * h;
    }
    float tot = block_reduce_sum(acc);
    if (t == 0) push[0] = tot / (float)(MM * (MM - 1));
}

__global__ void __launch_bounds__(NTHR, 4)
k_pull(const float4* __restrict__ o4,
       const int* __restrict__ labels,
       const int* __restrict__ sub,
       const float* __restrict__ mus,
       const float* __restrict__ invw,
       float* __restrict__ pull_part,
       int n) {
    __shared__ float muL[DD * SEGS];  // seg-major (matches ws mus layout)
    __shared__ float siw[SEGS];
    for (int i = threadIdx.x; i < DD * SEGS; i += NTHR) muL[i] = mus[i];
    for (int i = threadIdx.x; i < SEGS; i += NTHR) siw[i] = invw[i];
    __syncthreads();

    float4 m0, m1, m2, m3;
    float iw = 0.0f;
    int cur = -1;
    float acc = 0.0f;

    const int base = blockIdx.x * CHUNK + threadIdx.x;
    #pragma unroll
    for (int it = 0; it < CHUNK / NTHR; ++it) {
        int p = base + it * NTHR;
        if (p >= n) break;
        float4 a = o4[4 * p + 0];
        float4 b = o4[4 * p + 1];
        float4 c = o4[4 * p + 2];
        float4 e = o4[4 * p + 3];
        int seg = sub[p] * MM + labels[p];
        if (seg != cur) {              // once per thread for canonical input
            cur = seg;
            m0 = *(const float4*)&muL[seg * DD +  0];
            m1 = *(const float4*)&muL[seg * DD +  4];
            m2 = *(const float4*)&muL[seg * DD +  8];
            m3 = *(const float4*)&muL[seg * DD + 12];
            iw = siw[seg];
        }
        float ss = a.x*a.x + a.y*a.y + a.z*a.z + a.w*a.w
                 + b.x*b.x + b.y*b.y + b.z*b.z + b.w*b.w
                 + c.x*c.x + c.y*c.y + c.z*c.z + c.w*c.w
                 + e.x*e.x + e.y*e.y + e.z*e.z + e.w*e.w;
        float rn = 1.0f / (sqrtf(ss) + NEPS);
        float dist;
        dist  = fabsf(m0.x - a.x * rn) + fabsf(m0.y - a.y * rn)
              + fabsf(m0.z - a.z * rn) + fabsf(m0.w - a.w * rn);
        dist += fabsf(m1.x - b.x * rn) + fabsf(m1.y - b.y * rn)
              + fabsf(m1.z - b.z * rn) + fabsf(m1.w - b.w * rn);
        dist += fabsf(m2.x - c.x * rn) + fabsf(m2.y - c.y * rn)
              + fabsf(m2.z - c.z * rn) + fabsf(m2.w - c.w * rn);
        dist += fabsf(m3.x - e.x * rn) + fabsf(m3.y - e.y * rn)
              + fabsf(m3.z - e.z * rn) + fabsf(m3.w - e.w * rn);
        float h = dist - DELTA_V;
        if (h > 0.0f) acc = fmaf(h * h, iw, acc);
    }
    float tot = block_reduce_sum(acc);
    if (threadIdx.x == 0) pull_part[blockIdx.x] = tot;
}

__global__ void k_final(const float* __restrict__ ws, float* __restrict__ out) {
    const float* push      = ws + 8704;
    const float* pull_part = ws + 8720;
    int t = threadIdx.x;
    float v = 0.0f;
    #pragma unroll
    for (int k = 0; k < NBLK / NTHR; ++k) v += pull_part[t + k * NTHR];
    float tot = block_reduce_sum(v);
    if (t == 0) out[0] = (tot + push[0]) * (1.0f / (float)BBATCH);
}

extern "C" void kernel_launch(void* const* d_in, const int* in_sizes, int n_in,
                              void* d_out, int out_size, void* d_ws, size_t ws_size,
                              hipStream_t stream) {
    const float* outputs = (const float*)d_in[0];
    const int* labels    = (const int*)d_in[1];
    const int* sub       = (const int*)d_in[2];
    int n = in_sizes[0] / DD;

    float* ws        = (float*)d_ws;
    float* seg_sum   = ws;
    float* seg_cnt   = ws + 4096;
    float* mus       = ws + 4352;
    float* invw      = ws + 8448;
    float* pull_part = ws + 8720;

    hipMemsetAsync(d_ws, 0, WS_ZERO_FLOATS * sizeof(float), stream);

    k_segsum<<<NBLK, NTHR, 0, stream>>>((const float4*)outputs, labels, sub,
                                        seg_sum, seg_cnt, n);
    k_finalize_push<<<1, NTHR, 0, stream>>>(ws);
    k_pull<<<NBLK, NTHR, 0, stream>>>((const float4*)outputs, labels, sub,
                                      mus, invw, pull_part, n);
    k_final<<<1, NTHR, 0, stream>>>(ws, (float*)d_out);
}